// Round 10
// baseline (180.941 us; speedup 1.0000x reference)
//
#include <hip/hip_runtime.h>
#include <math.h>

#define APM   32
#define NMOL  256
#define FEAT  100
#define NPAD  112
#define LAYERS 4
#define NTHREADS 1024
#define NWAVES   16
#define G_TBL 1024
#define TSTR  128            // table row stride (f32 elems)
#define X1STR 132            // sX1 row stride (f32 elems)

typedef _Float16 f16x8 __attribute__((ext_vector_type(8)));
typedef float    f32x4 __attribute__((ext_vector_type(4)));

// per-layer f16 frag-weight block layout in ws (element offsets)
#define L1F_OFF 0        // lin1f  14336
#define L2F_OFF 14336    // lin2f  14336
#define LVF_OFF 28672    // linf   14336
#define LWTOT   43008    // per layer
#define WTOTAL  (4*LWTOT) // 172032 f16 = 344064 B

#define PREP_BLOCKS 672  // 172032/256
#define TBL_BLOCKS  128  // 32 per layer, 32 s-points per block

__device__ __forceinline__ float sspf(float x){
  // ssp(x) = log(1+e^x) - log2 (direct form, R5)
  return __logf(1.0f + __expf(x)) - 0.69314718056f;
}

// ---------------------------------------------------------------------------
// Single prep launch (R7). Blocks [0,672): weight->MFMA-B-frag conversion
// (validated R3 layout). Blocks [672,800): edge-filter table build with
// w1/w2/biases LDS-staged, 32 grid points per block:
//   tbl[l][s][f] = cc(d_s) * ( ssp(ea(d_s)@W1 + b1) @ W2 + b2 )[f]
// f in [100,128) stored 0 so gather feature-pad lanes read exact zeros.
// ---------------------------------------------------------------------------
__global__ __launch_bounds__(256) void prep_all(
    const float* __restrict__ lin1_w, const float* __restrict__ lin2_w,
    const float* __restrict__ lin_w,
    const float* __restrict__ mlp_w1, const float* __restrict__ mlp_b1,
    const float* __restrict__ mlp_w2, const float* __restrict__ mlp_b2,
    _Float16* __restrict__ outw, float* __restrict__ tbl)
{
  if (blockIdx.x < PREP_BLOCKS){
    int gid = blockIdx.x*256 + threadIdx.x;    // < 172032 exactly
    int l = gid / LWTOT;
    int r = gid - l*LWTOT;
    const float* W; int e;
    if (r < 14336)      { W = lin1_w + l*10000; e = r; }
    else if (r < 28672) { W = lin2_w + l*10000; e = r - 14336; }
    else                { W = lin_w  + l*10000; e = r - 28672; }
    int j = e & 7, L = (e >> 3) & 63, tile = e >> 9;
    int kc = tile / 7, nt = tile - kc*7;
    int k = kc*32 + ((L >> 4) << 3) + j;
    int f = nt*16 + (L & 15);
    float v = (k < 100 && f < FEAT) ? W[k*FEAT + f] : 0.0f;
    outw[gid] = (_Float16)v;
    return;
  }
  // ---- table segment ----
  __shared__ float sW2[10000];
  __shared__ float sW1[2500];
  __shared__ float sB1[100], sB2[100];
  __shared__ float sT[4][100];
  int bid = blockIdx.x - PREP_BLOCKS;
  int l = bid >> 5;                        // 32 blocks per layer
  int s0 = (bid & 31) * 32;
  int tid = threadIdx.x, wv = tid >> 6, lane = tid & 63;
  for (int i = tid; i < 10000; i += 256) sW2[i] = mlp_w2[l*10000 + i];
  for (int i = tid; i < 2500;  i += 256) sW1[i] = mlp_w1[l*2500 + i];
  if (tid < 100) sB1[tid] = mlp_b1[l*100 + tid];
  if (tid >= 128 && tid < 228) sB2[tid-128] = mlp_b2[l*100 + tid-128];
  __syncthreads();
  #pragma unroll 1
  for (int si = 0; si < 8; si++){
    int s = s0 + wv*8 + si;
    float d = 6.0f * (float)s / (float)(G_TBL - 1);
    float ea[25];
    #pragma unroll
    for (int g = 0; g < 25; g++){
      float u = d - 0.25f*(float)g;
      ea[g] = __expf(-8.0f*u*u);
    }
    #pragma unroll
    for (int kk = 0; kk < 2; kk++){
      int k = lane + kk*64;
      if (k < 100){
        float acc = sB1[k];
        #pragma unroll
        for (int g = 0; g < 25; g++)
          acc += ea[g] * sW1[g*100 + k];
        sT[wv][k] = sspf(acc);
      }
    }
    // wave-local LDS RAW: in-order DS + compiler lgkmcnt (validated R6)
    float cc = 0.5f*(__cosf(d*0.52359877559f) + 1.0f);
    #pragma unroll
    for (int ff = 0; ff < 2; ff++){
      int f = lane + ff*64;
      float o = 0.0f;
      if (f < 100){
        o = sB2[f];
        for (int k = 0; k < 100; k++)
          o += sT[wv][k] * sW2[k*100 + f];
        o *= cc;
      }
      tbl[((size_t)l*G_TBL + s)*TSTR + f] = o;   // f in [100,128) -> 0
    }
  }
}

// ---------------------------------------------------------------------------
// Whole network per molecule in one block. 1024 thr = 16 waves, 1 block/CU.
// R9 got 69us; counters showed 65% of wall = latency/barrier bubbles (VALU
// 34%, MFMA 1.6%, HBM 1.8%). R10: (1) sWA LDS staging DELETED — every GEMM
// B-frag was read from LDS exactly once per block, so global->LDS->reg was a
// pure extra copy; B-frags now read straight from L2-resident wfrag (16B/lane
// coalesced). Kills cpw VALU/DS work + 86KB LDS (141K->62K). (2) gather is a
// manual 1-deep double-buffered pipeline (load batch b+1 || lerp batch b) —
// R9's unroll-1 loop ate the full ~250cy L2 round-trip per round. (3) table
// index/frac (sOff/sFr) precomputed once at init: d is layer-invariant.
// NaN-safety (R7 lesson) unchanged: tbl cols>=100 exact 0, sX1 pad cols
// zeroed, gather covers sAf cols 0..127 (k-pad refresh).
// MFMA layouts (validated R3): A: m=lane&15,k=(lane>>4)*8+j ; C/D:
// n=lane&15, m=(lane>>4)*4+r.
// ---------------------------------------------------------------------------
__global__ __launch_bounds__(1024)
__attribute__((amdgpu_waves_per_eu(4, 4)))
void schnet_mega(
    const int* __restrict__ z, const float* __restrict__ pos,
    const float* __restrict__ emb, const _Float16* __restrict__ wf,
    const float* __restrict__ tbl,
    const float* __restrict__ lin2_b, const float* __restrict__ lin_b,
    const float* __restrict__ out_w1, const float* __restrict__ out_b1,
    const float* __restrict__ out_w2, const float* __restrict__ out_b2,
    float* __restrict__ out)
{
  __shared__ __align__(16) _Float16 sAf[APM*136];   // A-frag f16 (h / agg)
  __shared__ __align__(16) _Float16 sBf[APM*136];   // A-frag f16 (t2)
  __shared__ __align__(16) float    sX1[APM*X1STR]; // x1 fp32 row-major
  __shared__ __align__(16) float    sH [APM*NPAD];  // h state fp32
  __shared__ float sD  [APM*33];                    // distances (init only)
  __shared__ int   sOff[APM*33];                    // tbl row offset per edge
  __shared__ float sFr [APM*33];                    // lerp fraction per edge
  __shared__ float sPos[96];
  __shared__ float sPart[NWAVES];

  int tid = threadIdx.x, lane = tid & 63, wv = tid >> 6;
  int q = lane >> 4, n = lane & 15;
  int mol = blockIdx.x, mb = mol*APM;

  // ---------------- init ----------------
  if (tid < 96) sPos[tid] = pos[mb*3 + tid];
  if (tid < 512){                              // zero sBf k-pad cols 112..127
    int r0 = tid >> 4, c0 = 112 + (tid & 15);
    sBf[r0*136 + c0] = (_Float16)0.0f;
  }
  for (int i = tid; i < APM*20; i += NTHREADS){ // zero sX1 pad cols 112..131
    int r = i/20, c = 112 + (i - r*20);
    sX1[r*X1STR + c] = 0.0f;
  }
  for (int i = tid; i < APM*136; i += NTHREADS){ // h init (fp32 + f16 frag)
    int r = i/136, c = i - r*136;
    float v = (c < FEAT) ? emb[z[mb+r]*FEAT + c] : 0.0f;
    sAf[i] = (_Float16)v;
    if (c < NPAD) sH[r*NPAD + c] = v;
  }
  __syncthreads();
  for (int p = tid; p < APM*APM; p += NTHREADS){  // distances
    int i = p >> 5, j = p & 31;
    float dx = sPos[i*3+0]-sPos[j*3+0];
    float dy = sPos[i*3+1]-sPos[j*3+1];
    float dz = sPos[i*3+2]-sPos[j*3+2];
    float d2 = dx*dx + dy*dy + dz*dz;
    sD[i*33+j] = (d2 > 36.0f) ? 6.0f : sqrtf(d2);
  }
  __syncthreads();
  if (tid < APM){       // drop self + 3 farthest -> d=6 (tbl=0); emit off/fr
    float dd[32];
    #pragma unroll
    for (int j = 0; j < 32; j++) dd[j] = sD[tid*33+j];
    dd[tid] = 1e30f;
    unsigned dropped = 0u;
    for (int rr = 0; rr < 4; rr++){
      float mx = -1.0f; int mj = 0;
      #pragma unroll
      for (int j = 0; j < 32; j++){
        bool ok = !((dropped>>j)&1u) && (dd[j] > mx);
        mx = ok ? dd[j] : mx;  mj = ok ? j : mj;
      }
      dropped |= 1u << mj;
    }
    #pragma unroll
    for (int j = 0; j < 32; j++){
      float d = ((dropped>>j)&1u) ? 6.0f : dd[j];
      float un = d * (float)((G_TBL-1)/6.0);
      int s = (int)un;
      s = (s > G_TBL-2) ? (G_TBL-2) : s;
      sOff[tid*33+j] = s*TSTR;
      sFr [tid*33+j] = un - (float)s;
    }
  }
  __syncthreads();

  // ---------------- interaction layers (4 barriers each) ----------------
  for (int l = 0; l < LAYERS; l++){
    const _Float16* w1b = wf + l*LWTOT + L1F_OFF;   // lin1f (global, L2-hot)
    const _Float16* w2b = wf + l*LWTOT + L2F_OFF;   // lin2f
    const _Float16* wvb = wf + l*LWTOT + LVF_OFF;   // linf
    const float* tb = tbl + (size_t)l*G_TBL*TSTR;
    // ---- B: x1 = h @ lin1 -> sX1 row-major fp32 ----
    for (int tau = wv; tau < 14; tau += NWAVES){
      int mt = tau/7, nt = tau - mt*7;
      f32x4 acc = {0.0f,0.0f,0.0f,0.0f};
      #pragma unroll
      for (int kc = 0; kc < 4; kc++){
        f16x8 av = *(const f16x8*)&sAf[(mt*16+n)*136 + kc*32 + q*8];
        f16x8 bv = *(const f16x8*)&w1b[((kc*7+nt)*64 + lane)*8];
        acc = __builtin_amdgcn_mfma_f32_16x16x32_f16(av, bv, acc, 0, 0, 0);
      }
      #pragma unroll
      for (int r = 0; r < 4; r++)
        sX1[(mt*16+q*4+r)*X1STR + nt*16+n] = acc[r];
    }
    __syncthreads();
    // ---- C: half-wave table gather, 1-deep pipelined (batch = 4 edges) ----
    {
      int half = lane >> 5, L = lane & 31;
      int a = wv*2 + half, arow = a*33;
      float ag0=0.0f, ag1=0.0f, ag2=0.0f, ag3=0.0f;
      f32x4 A0[4], A1[4]; float fA[4];
      f32x4 B0[4], B1[4]; float fB[4];

#define GLD(J0, V0, V1, FR)                                            \
      { _Pragma("unroll")                                              \
        for (int u = 0; u < 4; u++){                                   \
          const float* r0 = tb + (sOff[arow + (J0) + u] + L);          \
          FR[u] = sFr[arow + (J0) + u];                                \
          V0[u][0] = r0[0];       V0[u][1] = r0[32];                   \
          V0[u][2] = r0[64];      V0[u][3] = r0[96];                   \
          V1[u][0] = r0[TSTR];    V1[u][1] = r0[TSTR+32];              \
          V1[u][2] = r0[TSTR+64]; V1[u][3] = r0[TSTR+96];              \
        } }
#define GCMP(J0, V0, V1, FR)                                           \
      { _Pragma("unroll")                                              \
        for (int u = 0; u < 4; u++){                                   \
          const float* xp = &sX1[((J0)+u)*X1STR + L];                  \
          f32x4 wl_ = V0[u] + FR[u]*(V1[u] - V0[u]);                   \
          ag0 += wl_[0]*xp[0];  ag1 += wl_[1]*xp[32];                  \
          ag2 += wl_[2]*xp[64]; ag3 += wl_[3]*xp[96];                  \
        } }

      GLD(0, A0, A1, fA)
      #pragma unroll
      for (int b = 0; b < 8; b += 2){
        GLD((b+1)*4, B0, B1, fB)
        GCMP(b*4, A0, A1, fA)
        if (b+2 < 8) GLD((b+2)*4, A0, A1, fA)
        GCMP((b+1)*4, B0, B1, fB)
      }
#undef GLD
#undef GCMP
      int ab = a*136 + L;                    // cols 0..127: agg + k-pad(0)
      sAf[ab]    = (_Float16)ag0;
      sAf[ab+32] = (_Float16)ag1;
      sAf[ab+64] = (_Float16)ag2;
      sAf[ab+96] = (_Float16)ag3;
    }
    __syncthreads();
    // ---- D: t2 = ssp(agg @ lin2 + b2l) -> sBf f16 ----
    for (int tau = wv; tau < 14; tau += NWAVES){
      int mt = tau/7, nt = tau - mt*7;
      f32x4 acc = {0.0f,0.0f,0.0f,0.0f};
      #pragma unroll
      for (int kc = 0; kc < 4; kc++){
        f16x8 av = *(const f16x8*)&sAf[(mt*16+n)*136 + kc*32 + q*8];
        f16x8 bv = *(const f16x8*)&w2b[((kc*7+nt)*64 + lane)*8];
        acc = __builtin_amdgcn_mfma_f32_16x16x32_f16(av, bv, acc, 0, 0, 0);
      }
      int f = nt*16 + n;
      float bb = (f < FEAT) ? lin2_b[l*FEAT + f] : 0.0f;
      #pragma unroll
      for (int r = 0; r < 4; r++)
        sBf[(mt*16+q*4+r)*136 + f] = (_Float16)sspf(acc[r] + bb);
    }
    __syncthreads();
    // ---- E: v = t2 @ lin + bl ; h += v ; sAf = f16(h) ----
    for (int tau = wv; tau < 14; tau += NWAVES){
      int mt = tau/7, nt = tau - mt*7;
      f32x4 acc = {0.0f,0.0f,0.0f,0.0f};
      #pragma unroll
      for (int kc = 0; kc < 4; kc++){
        f16x8 av = *(const f16x8*)&sBf[(mt*16+n)*136 + kc*32 + q*8];
        f16x8 bv = *(const f16x8*)&wvb[((kc*7+nt)*64 + lane)*8];
        acc = __builtin_amdgcn_mfma_f32_16x16x32_f16(av, bv, acc, 0, 0, 0);
      }
      int f = nt*16 + n;
      if (f < FEAT){
        float bb = lin_b[l*FEAT + f];
        #pragma unroll
        for (int r = 0; r < 4; r++){
          int row = mt*16 + q*4 + r;
          float hn = sH[row*NPAD + f] + acc[r] + bb;
          sH[row*NPAD + f] = hn;
          sAf[row*136 + f] = (_Float16)hn;
        }
      }
    }
    __syncthreads();
  }

  // ---------------- readout (weights direct from L2) ----------------
  float ob2 = out_b2[0];
  float partial = 0.0f;
  for (int t = 0; t < 2; t++){
    int a = wv*2 + t;
    float u = 0.0f;
    if (lane < 50){
      u = out_b1[lane];
      #pragma unroll 4
      for (int c = 0; c < FEAT; c++)
        u += sH[a*NPAD + c] * out_w1[c*50 + lane];
      u = sspf(u) * out_w2[lane];
    }
    #pragma unroll
    for (int s = 1; s < 64; s <<= 1) u += __shfl_xor(u, s);
    partial += u + ob2;
  }
  if (lane == 0) sPart[wv] = partial;
  __syncthreads();
  if (tid == 0){
    float s = 0.0f;
    #pragma unroll
    for (int i = 0; i < NWAVES; i++) s += sPart[i];
    out[mol] = s;
  }
}

extern "C" void kernel_launch(void* const* d_in, const int* in_sizes, int n_in,
                              void* d_out, int out_size, void* d_ws, size_t ws_size,
                              hipStream_t stream)
{
  const int*   z      = (const int*)  d_in[0];
  const float* pos    = (const float*)d_in[1];
  /* d_in[2] = ptr: molecules are fixed 32-atom blocks; unused */
  const float* emb    = (const float*)d_in[3];
  const float* mlp_w1 = (const float*)d_in[4];
  const float* mlp_b1 = (const float*)d_in[5];
  const float* mlp_w2 = (const float*)d_in[6];
  const float* mlp_b2 = (const float*)d_in[7];
  const float* lin1_w = (const float*)d_in[8];
  const float* lin2_w = (const float*)d_in[9];
  const float* lin2_b = (const float*)d_in[10];
  const float* lin_w  = (const float*)d_in[11];
  const float* lin_b  = (const float*)d_in[12];
  const float* out_w1 = (const float*)d_in[13];
  const float* out_b1 = (const float*)d_in[14];
  const float* out_w2 = (const float*)d_in[15];
  const float* out_b2 = (const float*)d_in[16];

  _Float16* wfrag = (_Float16*)d_ws;                    // 344064 B
  float*    tbl   = (float*)((char*)d_ws + WTOTAL*2);   // 4*1024*128*4 = 2 MB

  prep_all<<<PREP_BLOCKS + TBL_BLOCKS, 256, 0, stream>>>(
      lin1_w, lin2_w, lin_w, mlp_w1, mlp_b1, mlp_w2, mlp_b2, wfrag, tbl);
  schnet_mega<<<NMOL, NTHREADS, 0, stream>>>(z, pos, emb, wfrag, tbl,
      lin2_b, lin_b, out_w1, out_b1, out_w2, out_b2, (float*)d_out);
}

// Round 11
// 176.699 us; speedup vs baseline: 1.0240x; 1.0240x over previous
//
#include <hip/hip_runtime.h>
#include <math.h>

#define APM   32
#define NMOL  256
#define FEAT  100
#define NPAD  112
#define LAYERS 4
#define NTHREADS 1024
#define NWAVES   16
#define G_TBL 1024
#define PSTR  128            // pair-table row stride (f16x2 elems = 4B each)
#define X1STR 132            // sX1 row stride (f32 elems)
#define KEDGE 28             // active edges per atom (= reference K)

typedef _Float16 f16x8 __attribute__((ext_vector_type(8)));
typedef _Float16 f16x2 __attribute__((ext_vector_type(2)));
typedef float    f32x4 __attribute__((ext_vector_type(4)));

// per-layer f16 frag-weight block layout in ws (element offsets)
#define L1F_OFF 0        // lin1f  14336
#define L2F_OFF 14336    // lin2f  14336
#define LVF_OFF 28672    // linf   14336
#define LWTOT   43008    // per layer
#define WTOTAL  (4*LWTOT) // 172032 f16 = 344064 B

#define PREP_BLOCKS 672  // 172032/256
#define TBL_BLOCKS  128  // 32 per layer, 32 s-points per block

__device__ __forceinline__ float sspf(float x){
  // ssp(x) = log(1+e^x) - log2 (direct form, R5)
  return __logf(1.0f + __expf(x)) - 0.69314718056f;
}

// ---------------------------------------------------------------------------
// Single prep launch. Blocks [0,672): weight->MFMA-B-frag conversion
// (validated R3 layout). Blocks [672,800): edge-filter PAIR table build.
// R11: tblp[l][s][f] = ( f16 Wf(d_s)[f], f16 Wf(d_{s+1})[f] ) — one 4B load
// gives both lerp endpoints (halves gather bytes + instructions). Each block
// computes 33 grid points into LDS (one overlap), writes 32 pair-rows.
// f in [100,128) stored 0 so gather feature-pad lanes read exact zeros.
// ---------------------------------------------------------------------------
__global__ __launch_bounds__(256) void prep_all(
    const float* __restrict__ lin1_w, const float* __restrict__ lin2_w,
    const float* __restrict__ lin_w,
    const float* __restrict__ mlp_w1, const float* __restrict__ mlp_b1,
    const float* __restrict__ mlp_w2, const float* __restrict__ mlp_b2,
    _Float16* __restrict__ outw, f16x2* __restrict__ tblp)
{
  if (blockIdx.x < PREP_BLOCKS){
    int gid = blockIdx.x*256 + threadIdx.x;    // < 172032 exactly
    int l = gid / LWTOT;
    int r = gid - l*LWTOT;
    const float* W; int e;
    if (r < 14336)      { W = lin1_w + l*10000; e = r; }
    else if (r < 28672) { W = lin2_w + l*10000; e = r - 14336; }
    else                { W = lin_w  + l*10000; e = r - 28672; }
    int j = e & 7, L = (e >> 3) & 63, tile = e >> 9;
    int kc = tile / 7, nt = tile - kc*7;
    int k = kc*32 + ((L >> 4) << 3) + j;
    int f = nt*16 + (L & 15);
    float v = (k < 100 && f < FEAT) ? W[k*FEAT + f] : 0.0f;
    outw[gid] = (_Float16)v;
    return;
  }
  // ---- table segment ----
  __shared__ float sW2[10000];
  __shared__ float sW1[2500];
  __shared__ float sB1[100], sB2[100];
  __shared__ float sT[4][100];
  __shared__ float sV[33][128];            // 33 grid points (1 overlap)
  int bid = blockIdx.x - PREP_BLOCKS;
  int l = bid >> 5;                        // 32 blocks per layer
  int s0 = (bid & 31) * 32;
  int tid = threadIdx.x, wv = tid >> 6, lane = tid & 63;
  for (int i = tid; i < 10000; i += 256) sW2[i] = mlp_w2[l*10000 + i];
  for (int i = tid; i < 2500;  i += 256) sW1[i] = mlp_w1[l*2500 + i];
  if (tid < 100) sB1[tid] = mlp_b1[l*100 + tid];
  if (tid >= 128 && tid < 228) sB2[tid-128] = mlp_b2[l*100 + tid-128];
  if (tid < 128){ sV[32][tid] = 0.0f; }    // pad cols of all points zeroed
  for (int i = tid; i < 33*128; i += 256)  // zero f>=100 cols (and all, cheap)
    ((float*)sV)[i] = 0.0f;
  __syncthreads();
  #pragma unroll 1
  for (int si = 0; si < 9; si++){          // wave wv: points wv*8..wv*8+7;
    int li = wv*8 + si;                    // wave 3 additionally point 32
    if (li > 32 || (si == 8 && wv != 3)) continue;
    int s = s0 + li; if (s > G_TBL-1) s = G_TBL-1;
    float d = 6.0f * (float)s / (float)(G_TBL - 1);
    float ea[25];
    #pragma unroll
    for (int g = 0; g < 25; g++){
      float u = d - 0.25f*(float)g;
      ea[g] = __expf(-8.0f*u*u);
    }
    #pragma unroll
    for (int kk = 0; kk < 2; kk++){
      int k = lane + kk*64;
      if (k < 100){
        float acc = sB1[k];
        #pragma unroll
        for (int g = 0; g < 25; g++)
          acc += ea[g] * sW1[g*100 + k];
        sT[wv][k] = sspf(acc);
      }
    }
    // wave-local LDS RAW: in-order DS + compiler lgkmcnt (validated R6)
    float cc = 0.5f*(__cosf(d*0.52359877559f) + 1.0f);
    #pragma unroll
    for (int ff = 0; ff < 2; ff++){
      int f = lane + ff*64;
      if (f < 100){
        float o = sB2[f];
        for (int k = 0; k < 100; k++)
          o += sT[wv][k] * sW2[k*100 + f];
        sV[li][f] = o * cc;
      }
    }
  }
  __syncthreads();
  for (int i = tid; i < 32*128; i += 256){ // write pair rows s0..s0+31
    int s = i >> 7, f = i & 127;
    f16x2 pr = { (_Float16)sV[s][f], (_Float16)sV[s+1][f] };
    tblp[((size_t)l*G_TBL + s0 + s)*PSTR + f] = pr;
  }
}

// ---------------------------------------------------------------------------
// Whole network per molecule in one block. 1024 thr = 16 waves, 1 block/CU.
// R10 plateaued at ~72us: gather reads 2 x 512B table rows per edge = ~1GB
// L2 traffic/dispatch (14TB/s sustained) — the gather IS the wall. R11:
// (1) pair-packed f16 table — 1 load = both lerp endpoints: bytes/edge
// 1KB->512B, load instrs halved; (2) dropped edges compacted away at init
// (exactly 4/32 dropped = K=28, contribution ~1e-8): 7 gather batches of 4.
// Net ~440MB L2 traffic. GEMM B-frags stay global (L2-hot, read-once).
// NaN-safety (R7): table pad cols exact 0, sX1 pad cols zeroed, gather
// covers sAf cols 0..127 (k-pad refresh).
// MFMA layouts (validated R3): A: m=lane&15,k=(lane>>4)*8+j ; C/D:
// n=lane&15, m=(lane>>4)*4+r.
// ---------------------------------------------------------------------------
__global__ __launch_bounds__(1024)
__attribute__((amdgpu_waves_per_eu(4, 4)))
void schnet_mega(
    const int* __restrict__ z, const float* __restrict__ pos,
    const float* __restrict__ emb, const _Float16* __restrict__ wf,
    const f16x2* __restrict__ tblp,
    const float* __restrict__ lin2_b, const float* __restrict__ lin_b,
    const float* __restrict__ out_w1, const float* __restrict__ out_b1,
    const float* __restrict__ out_w2, const float* __restrict__ out_b2,
    float* __restrict__ out)
{
  __shared__ __align__(16) _Float16 sAf[APM*136];   // A-frag f16 (h / agg)
  __shared__ __align__(16) _Float16 sBf[APM*136];   // A-frag f16 (t2)
  __shared__ __align__(16) float    sX1[APM*X1STR]; // x1 fp32 row-major
  __shared__ __align__(16) float    sH [APM*NPAD];  // h state fp32
  __shared__ float sD  [APM*33];                    // distances (init only)
  __shared__ int   sOffC[APM*KEDGE];                // compacted tbl row offs
  __shared__ float sFrC [APM*KEDGE];                // compacted lerp fracs
  __shared__ int   sJx  [APM*KEDGE];                // compacted src atom j
  __shared__ float sPos[96];
  __shared__ float sPart[NWAVES];

  int tid = threadIdx.x, lane = tid & 63, wv = tid >> 6;
  int q = lane >> 4, n = lane & 15;
  int mol = blockIdx.x, mb = mol*APM;

  // ---------------- init ----------------
  if (tid < 96) sPos[tid] = pos[mb*3 + tid];
  if (tid < 512){                              // zero sBf k-pad cols 112..127
    int r0 = tid >> 4, c0 = 112 + (tid & 15);
    sBf[r0*136 + c0] = (_Float16)0.0f;
  }
  for (int i = tid; i < APM*20; i += NTHREADS){ // zero sX1 pad cols 112..131
    int r = i/20, c = 112 + (i - r*20);
    sX1[r*X1STR + c] = 0.0f;
  }
  for (int i = tid; i < APM*136; i += NTHREADS){ // h init (fp32 + f16 frag)
    int r = i/136, c = i - r*136;
    float v = (c < FEAT) ? emb[z[mb+r]*FEAT + c] : 0.0f;
    sAf[i] = (_Float16)v;
    if (c < NPAD) sH[r*NPAD + c] = v;
  }
  __syncthreads();
  for (int p = tid; p < APM*APM; p += NTHREADS){  // distances
    int i = p >> 5, j = p & 31;
    float dx = sPos[i*3+0]-sPos[j*3+0];
    float dy = sPos[i*3+1]-sPos[j*3+1];
    float dz = sPos[i*3+2]-sPos[j*3+2];
    float d2 = dx*dx + dy*dy + dz*dz;
    sD[i*33+j] = (d2 > 36.0f) ? 6.0f : sqrtf(d2);
  }
  __syncthreads();
  if (tid < APM){   // drop self + 3 farthest; emit compacted {off, fr, j}
    float dd[32];
    #pragma unroll
    for (int j = 0; j < 32; j++) dd[j] = sD[tid*33+j];
    dd[tid] = 1e30f;
    unsigned dropped = 0u;
    for (int rr = 0; rr < 4; rr++){
      float mx = -1.0f; int mj = 0;
      #pragma unroll
      for (int j = 0; j < 32; j++){
        bool ok = !((dropped>>j)&1u) && (dd[j] > mx);
        mx = ok ? dd[j] : mx;  mj = ok ? j : mj;
      }
      dropped |= 1u << mj;
    }
    int e = 0;
    for (int j = 0; j < 32; j++){
      if ((dropped>>j)&1u) continue;
      float un = dd[j] * (float)((G_TBL-1)/6.0);
      int s = (int)un;
      s = (s > G_TBL-2) ? (G_TBL-2) : s;
      sOffC[tid*KEDGE + e] = s*PSTR;
      sFrC [tid*KEDGE + e] = un - (float)s;
      sJx  [tid*KEDGE + e] = j;
      e++;
    }
  }
  __syncthreads();

  // ---------------- interaction layers (4 barriers each) ----------------
  for (int l = 0; l < LAYERS; l++){
    const _Float16* w1b = wf + l*LWTOT + L1F_OFF;   // lin1f (global, L2-hot)
    const _Float16* w2b = wf + l*LWTOT + L2F_OFF;   // lin2f
    const _Float16* wvb = wf + l*LWTOT + LVF_OFF;   // linf
    const f16x2* tb = tblp + (size_t)l*G_TBL*PSTR;
    // ---- B: x1 = h @ lin1 -> sX1 row-major fp32 ----
    for (int tau = wv; tau < 14; tau += NWAVES){
      int mt = tau/7, nt = tau - mt*7;
      f32x4 acc = {0.0f,0.0f,0.0f,0.0f};
      #pragma unroll
      for (int kc = 0; kc < 4; kc++){
        f16x8 av = *(const f16x8*)&sAf[(mt*16+n)*136 + kc*32 + q*8];
        f16x8 bv = *(const f16x8*)&w1b[((kc*7+nt)*64 + lane)*8];
        acc = __builtin_amdgcn_mfma_f32_16x16x32_f16(av, bv, acc, 0, 0, 0);
      }
      #pragma unroll
      for (int r = 0; r < 4; r++)
        sX1[(mt*16+q*4+r)*X1STR + nt*16+n] = acc[r];
    }
    __syncthreads();
    // ---- C: half-wave pair-table gather, 1-deep pipelined, 7 batches ----
    {
      int half = lane >> 5, L = lane & 31;
      int a = wv*2 + half, ar = a*KEDGE;
      float ag0=0.0f, ag1=0.0f, ag2=0.0f, ag3=0.0f;
      f16x2 PA[4][4]; float fA[4]; int jA[4];
      f16x2 PB[4][4]; float fB[4]; int jB[4];

#define GLD(E0, P, FR, JV)                                             \
      { _Pragma("unroll")                                              \
        for (int u = 0; u < 4; u++){                                   \
          int e = ar + (E0) + u;                                       \
          const f16x2* rp = tb + (sOffC[e] + L);                       \
          FR[u] = sFrC[e]; JV[u] = sJx[e];                             \
          P[u][0] = rp[0];  P[u][1] = rp[32];                          \
          P[u][2] = rp[64]; P[u][3] = rp[96];                          \
        } }
#define GCMP(P, FR, JV)                                                \
      { _Pragma("unroll")                                              \
        for (int u = 0; u < 4; u++){                                   \
          const float* xp = &sX1[JV[u]*X1STR + L];                     \
          float fr = FR[u];                                            \
          float v0, v1, w_;                                            \
          v0 = (float)P[u][0].x; v1 = (float)P[u][0].y;                \
          w_ = v0 + fr*(v1-v0); ag0 += w_*xp[0];                       \
          v0 = (float)P[u][1].x; v1 = (float)P[u][1].y;                \
          w_ = v0 + fr*(v1-v0); ag1 += w_*xp[32];                      \
          v0 = (float)P[u][2].x; v1 = (float)P[u][2].y;                \
          w_ = v0 + fr*(v1-v0); ag2 += w_*xp[64];                      \
          v0 = (float)P[u][3].x; v1 = (float)P[u][3].y;                \
          w_ = v0 + fr*(v1-v0); ag3 += w_*xp[96];                      \
        } }

      GLD(0, PA, fA, jA)
      #pragma unroll
      for (int b = 0; b < 7; b += 2){
        if (b+1 < 7) GLD((b+1)*4, PB, fB, jB)
        GCMP(PA, fA, jA)
        if (b+2 < 7) GLD((b+2)*4, PA, fA, jA)
        if (b+1 < 7) GCMP(PB, fB, jB)
      }
#undef GLD
#undef GCMP
      int ab = a*136 + L;                    // cols 0..127: agg + k-pad(0)
      sAf[ab]    = (_Float16)ag0;
      sAf[ab+32] = (_Float16)ag1;
      sAf[ab+64] = (_Float16)ag2;
      sAf[ab+96] = (_Float16)ag3;
    }
    __syncthreads();
    // ---- D: t2 = ssp(agg @ lin2 + b2l) -> sBf f16 ----
    for (int tau = wv; tau < 14; tau += NWAVES){
      int mt = tau/7, nt = tau - mt*7;
      f32x4 acc = {0.0f,0.0f,0.0f,0.0f};
      #pragma unroll
      for (int kc = 0; kc < 4; kc++){
        f16x8 av = *(const f16x8*)&sAf[(mt*16+n)*136 + kc*32 + q*8];
        f16x8 bv = *(const f16x8*)&w2b[((kc*7+nt)*64 + lane)*8];
        acc = __builtin_amdgcn_mfma_f32_16x16x32_f16(av, bv, acc, 0, 0, 0);
      }
      int f = nt*16 + n;
      float bb = (f < FEAT) ? lin2_b[l*FEAT + f] : 0.0f;
      #pragma unroll
      for (int r = 0; r < 4; r++)
        sBf[(mt*16+q*4+r)*136 + f] = (_Float16)sspf(acc[r] + bb);
    }
    __syncthreads();
    // ---- E: v = t2 @ lin + bl ; h += v ; sAf = f16(h) ----
    for (int tau = wv; tau < 14; tau += NWAVES){
      int mt = tau/7, nt = tau - mt*7;
      f32x4 acc = {0.0f,0.0f,0.0f,0.0f};
      #pragma unroll
      for (int kc = 0; kc < 4; kc++){
        f16x8 av = *(const f16x8*)&sBf[(mt*16+n)*136 + kc*32 + q*8];
        f16x8 bv = *(const f16x8*)&wvb[((kc*7+nt)*64 + lane)*8];
        acc = __builtin_amdgcn_mfma_f32_16x16x32_f16(av, bv, acc, 0, 0, 0);
      }
      int f = nt*16 + n;
      if (f < FEAT){
        float bb = lin_b[l*FEAT + f];
        #pragma unroll
        for (int r = 0; r < 4; r++){
          int row = mt*16 + q*4 + r;
          float hn = sH[row*NPAD + f] + acc[r] + bb;
          sH[row*NPAD + f] = hn;
          sAf[row*136 + f] = (_Float16)hn;
        }
      }
    }
    __syncthreads();
  }

  // ---------------- readout (weights direct from L2) ----------------
  float ob2 = out_b2[0];
  float partial = 0.0f;
  for (int t = 0; t < 2; t++){
    int a = wv*2 + t;
    float u = 0.0f;
    if (lane < 50){
      u = out_b1[lane];
      #pragma unroll 4
      for (int c = 0; c < FEAT; c++)
        u += sH[a*NPAD + c] * out_w1[c*50 + lane];
      u = sspf(u) * out_w2[lane];
    }
    #pragma unroll
    for (int s = 1; s < 64; s <<= 1) u += __shfl_xor(u, s);
    partial += u + ob2;
  }
  if (lane == 0) sPart[wv] = partial;
  __syncthreads();
  if (tid == 0){
    float s = 0.0f;
    #pragma unroll
    for (int i = 0; i < NWAVES; i++) s += sPart[i];
    out[mol] = s;
  }
}

extern "C" void kernel_launch(void* const* d_in, const int* in_sizes, int n_in,
                              void* d_out, int out_size, void* d_ws, size_t ws_size,
                              hipStream_t stream)
{
  const int*   z      = (const int*)  d_in[0];
  const float* pos    = (const float*)d_in[1];
  /* d_in[2] = ptr: molecules are fixed 32-atom blocks; unused */
  const float* emb    = (const float*)d_in[3];
  const float* mlp_w1 = (const float*)d_in[4];
  const float* mlp_b1 = (const float*)d_in[5];
  const float* mlp_w2 = (const float*)d_in[6];
  const float* mlp_b2 = (const float*)d_in[7];
  const float* lin1_w = (const float*)d_in[8];
  const float* lin2_w = (const float*)d_in[9];
  const float* lin2_b = (const float*)d_in[10];
  const float* lin_w  = (const float*)d_in[11];
  const float* lin_b  = (const float*)d_in[12];
  const float* out_w1 = (const float*)d_in[13];
  const float* out_b1 = (const float*)d_in[14];
  const float* out_w2 = (const float*)d_in[15];
  const float* out_b2 = (const float*)d_in[16];

  _Float16* wfrag = (_Float16*)d_ws;                    // 344064 B
  f16x2*    tblp  = (f16x2*)((char*)d_ws + WTOTAL*2);   // 4*1024*128*4 = 2 MB

  prep_all<<<PREP_BLOCKS + TBL_BLOCKS, 256, 0, stream>>>(
      lin1_w, lin2_w, lin_w, mlp_w1, mlp_b1, mlp_w2, mlp_b2, wfrag, tblp);
  schnet_mega<<<NMOL, NTHREADS, 0, stream>>>(z, pos, emb, wfrag, tblp,
      lin2_b, lin_b, out_w1, out_b1, out_w2, out_b2, (float*)d_out);
}

// Round 12
// 172.666 us; speedup vs baseline: 1.0479x; 1.0234x over previous
//
#include <hip/hip_runtime.h>
#include <math.h>

#define APM   32
#define NMOL  256
#define FEAT  100
#define NPAD  112
#define LAYERS 4
#define NTHREADS 1024
#define NWAVES   16
#define G_TBL 4096           // nearest-neighbor grid (R12: 4x finer, no lerp)
#define TROW  128            // table row stride (f16 elems)
#define X1STR 132            // sX1 row stride (f32 elems)
#define KEDGE 28             // active edges per atom (= reference K)

typedef _Float16 f16x8 __attribute__((ext_vector_type(8)));
typedef _Float16 f16x2 __attribute__((ext_vector_type(2)));
typedef float    f32x4 __attribute__((ext_vector_type(4)));
typedef float    f32x2 __attribute__((ext_vector_type(2)));

// per-layer f16 frag-weight block layout in ws (element offsets)
#define L1F_OFF 0        // lin1f  14336
#define L2F_OFF 14336    // lin2f  14336
#define LVF_OFF 28672    // linf   14336
#define LWTOT   43008    // per layer
#define WTOTAL  (4*LWTOT) // 172032 f16 = 344064 B

#define PREP_BLOCKS 672  // 172032/256
#define TBL_BLOCKS  256  // 64 per layer, 64 s-points per block

__device__ __forceinline__ float sspf(float x){
  // ssp(x) = log(1+e^x) - log2 (direct form, R5)
  return __logf(1.0f + __expf(x)) - 0.69314718056f;
}

// ---------------------------------------------------------------------------
// Single prep launch. Blocks [0,672): weight->MFMA-B-frag conversion
// (validated R3 layout). Blocks [672,928): nearest-neighbor edge-filter
// table, f16:  tbn[l][s][f] = f16( cc(d_s) * (ssp(ea(d_s)@W1+b1)@W2+b2)[f] )
// d_s = 6*s/(G-1), G=4096. f in [100,128) stored 0 (gather pad lanes).
// k-chain matvec unrolled x4 with independent partials (breaks the 100-deep
// serial FMA chain; keeps prep flat despite 4x the grid points).
// ---------------------------------------------------------------------------
__global__ __launch_bounds__(256) void prep_all(
    const float* __restrict__ lin1_w, const float* __restrict__ lin2_w,
    const float* __restrict__ lin_w,
    const float* __restrict__ mlp_w1, const float* __restrict__ mlp_b1,
    const float* __restrict__ mlp_w2, const float* __restrict__ mlp_b2,
    _Float16* __restrict__ outw, _Float16* __restrict__ tbn)
{
  if (blockIdx.x < PREP_BLOCKS){
    int gid = blockIdx.x*256 + threadIdx.x;    // < 172032 exactly
    int l = gid / LWTOT;
    int r = gid - l*LWTOT;
    const float* W; int e;
    if (r < 14336)      { W = lin1_w + l*10000; e = r; }
    else if (r < 28672) { W = lin2_w + l*10000; e = r - 14336; }
    else                { W = lin_w  + l*10000; e = r - 28672; }
    int j = e & 7, L = (e >> 3) & 63, tile = e >> 9;
    int kc = tile / 7, nt = tile - kc*7;
    int k = kc*32 + ((L >> 4) << 3) + j;
    int f = nt*16 + (L & 15);
    float v = (k < 100 && f < FEAT) ? W[k*FEAT + f] : 0.0f;
    outw[gid] = (_Float16)v;
    return;
  }
  // ---- table segment ----
  __shared__ float sW2[10000];
  __shared__ float sW1[2500];
  __shared__ float sB1[100], sB2[100];
  __shared__ float sT[4][100];
  int bid = blockIdx.x - PREP_BLOCKS;
  int l = bid >> 6;                        // 64 blocks per layer
  int s0 = (bid & 63) * 64;                // 64 points per block
  int tid = threadIdx.x, wv = tid >> 6, lane = tid & 63;
  for (int i = tid; i < 10000; i += 256) sW2[i] = mlp_w2[l*10000 + i];
  for (int i = tid; i < 2500;  i += 256) sW1[i] = mlp_w1[l*2500 + i];
  if (tid < 100) sB1[tid] = mlp_b1[l*100 + tid];
  if (tid >= 128 && tid < 228) sB2[tid-128] = mlp_b2[l*100 + tid-128];
  __syncthreads();
  #pragma unroll 1
  for (int si = 0; si < 16; si++){         // wave wv: points wv*16..+15
    int s = s0 + wv*16 + si;
    float d = 6.0f * (float)s / (float)(G_TBL - 1);
    float ea[25];
    #pragma unroll
    for (int g = 0; g < 25; g++){
      float u = d - 0.25f*(float)g;
      ea[g] = __expf(-8.0f*u*u);
    }
    #pragma unroll
    for (int kk = 0; kk < 2; kk++){
      int k = lane + kk*64;
      if (k < 100){
        float acc = sB1[k];
        #pragma unroll
        for (int g = 0; g < 25; g++)
          acc += ea[g] * sW1[g*100 + k];
        sT[wv][k] = sspf(acc);
      }
    }
    // wave-local LDS RAW: in-order DS + compiler lgkmcnt (validated R6)
    float cc = 0.5f*(__cosf(d*0.52359877559f) + 1.0f);
    #pragma unroll
    for (int ff = 0; ff < 2; ff++){
      int f = lane + ff*64;
      float val = 0.0f;
      if (f < 100){
        float o0=0.0f, o1=0.0f, o2=0.0f, o3=0.0f;
        #pragma unroll
        for (int k = 0; k < 100; k += 4){   // 4 independent chains
          o0 += sT[wv][k  ] * sW2[(k  )*100 + f];
          o1 += sT[wv][k+1] * sW2[(k+1)*100 + f];
          o2 += sT[wv][k+2] * sW2[(k+2)*100 + f];
          o3 += sT[wv][k+3] * sW2[(k+3)*100 + f];
        }
        val = (sB2[f] + ((o0+o1)+(o2+o3))) * cc;
      }
      tbn[((size_t)l*G_TBL + s)*TROW + f] = (_Float16)val;
    }
  }
}

// ---------------------------------------------------------------------------
// Whole network per molecule in one block. 1024 thr = 16 waves, 1 block/CU.
// R11 hit 62us with lerp on a pair-packed table; VALU busy-time (~25us) was
// dominated by lerp math (5 VALU/feature). R12: nearest-neighbor on a 4x
// finer f16 table — per feature: 1 packed f16x2 load + cvt + fma. VALU/edge
// -60%, loads/batch 16->8, bytes/edge 512->256B (~235MB L2/dispatch).
// Nearest error (~1.5e-3/weight) is same order as R11's f16 quantization and
// far below the bf16 output-quant noise that sets the measured absmax.
// NaN-safety (R7): table pad cols exact 0, sX1 pad cols zeroed, gather
// covers sAf cols 0..127 (k-pad refresh).
// MFMA layouts (validated R3): A: m=lane&15,k=(lane>>4)*8+j ; C/D:
// n=lane&15, m=(lane>>4)*4+r.
// ---------------------------------------------------------------------------
__global__ __launch_bounds__(1024)
__attribute__((amdgpu_waves_per_eu(4, 4)))
void schnet_mega(
    const int* __restrict__ z, const float* __restrict__ pos,
    const float* __restrict__ emb, const _Float16* __restrict__ wf,
    const _Float16* __restrict__ tbn,
    const float* __restrict__ lin2_b, const float* __restrict__ lin_b,
    const float* __restrict__ out_w1, const float* __restrict__ out_b1,
    const float* __restrict__ out_w2, const float* __restrict__ out_b2,
    float* __restrict__ out)
{
  __shared__ __align__(16) _Float16 sAf[APM*136];   // A-frag f16 (h / agg)
  __shared__ __align__(16) _Float16 sBf[APM*136];   // A-frag f16 (t2)
  __shared__ __align__(16) float    sX1[APM*X1STR]; // x1 fp32 row-major
  __shared__ __align__(16) float    sH [APM*NPAD];  // h state fp32
  __shared__ float sD  [APM*33];                    // distances (init only)
  __shared__ int   sOffC[APM*KEDGE];                // nearest row offs (f16 e)
  __shared__ int   sJx  [APM*KEDGE];                // compacted src atom j
  __shared__ float sPos[96];
  __shared__ float sPart[NWAVES];

  int tid = threadIdx.x, lane = tid & 63, wv = tid >> 6;
  int q = lane >> 4, n = lane & 15;
  int mol = blockIdx.x, mb = mol*APM;

  // ---------------- init ----------------
  if (tid < 96) sPos[tid] = pos[mb*3 + tid];
  if (tid < 512){                              // zero sBf k-pad cols 112..127
    int r0 = tid >> 4, c0 = 112 + (tid & 15);
    sBf[r0*136 + c0] = (_Float16)0.0f;
  }
  for (int i = tid; i < APM*20; i += NTHREADS){ // zero sX1 pad cols 112..131
    int r = i/20, c = 112 + (i - r*20);
    sX1[r*X1STR + c] = 0.0f;
  }
  for (int i = tid; i < APM*136; i += NTHREADS){ // h init (fp32 + f16 frag)
    int r = i/136, c = i - r*136;
    float v = (c < FEAT) ? emb[z[mb+r]*FEAT + c] : 0.0f;
    sAf[i] = (_Float16)v;
    if (c < NPAD) sH[r*NPAD + c] = v;
  }
  __syncthreads();
  for (int p = tid; p < APM*APM; p += NTHREADS){  // distances
    int i = p >> 5, j = p & 31;
    float dx = sPos[i*3+0]-sPos[j*3+0];
    float dy = sPos[i*3+1]-sPos[j*3+1];
    float dz = sPos[i*3+2]-sPos[j*3+2];
    float d2 = dx*dx + dy*dy + dz*dz;
    sD[i*33+j] = (d2 > 36.0f) ? 6.0f : sqrtf(d2);
  }
  __syncthreads();
  if (tid < APM){   // drop self + 3 farthest; emit compacted {off, j}
    float dd[32];
    #pragma unroll
    for (int j = 0; j < 32; j++) dd[j] = sD[tid*33+j];
    dd[tid] = 1e30f;
    unsigned dropped = 0u;
    for (int rr = 0; rr < 4; rr++){
      float mx = -1.0f; int mj = 0;
      #pragma unroll
      for (int j = 0; j < 32; j++){
        bool ok = !((dropped>>j)&1u) && (dd[j] > mx);
        mx = ok ? dd[j] : mx;  mj = ok ? j : mj;
      }
      dropped |= 1u << mj;
    }
    int e = 0;
    for (int j = 0; j < 32; j++){
      if ((dropped>>j)&1u) continue;
      float un = dd[j] * (float)((G_TBL-1)/6.0);
      int s = (int)(un + 0.5f);              // nearest
      s = (s > G_TBL-1) ? (G_TBL-1) : s;
      sOffC[tid*KEDGE + e] = s*TROW;
      sJx  [tid*KEDGE + e] = j;
      e++;
    }
  }
  __syncthreads();

  // ---------------- interaction layers (4 barriers each) ----------------
  for (int l = 0; l < LAYERS; l++){
    const _Float16* w1b = wf + l*LWTOT + L1F_OFF;   // lin1f (global, L2-hot)
    const _Float16* w2b = wf + l*LWTOT + L2F_OFF;   // lin2f
    const _Float16* wvb = wf + l*LWTOT + LVF_OFF;   // linf
    const _Float16* tb = tbn + (size_t)l*G_TBL*TROW;
    // ---- B: x1 = h @ lin1 -> sX1 row-major fp32 ----
    for (int tau = wv; tau < 14; tau += NWAVES){
      int mt = tau/7, nt = tau - mt*7;
      f32x4 acc = {0.0f,0.0f,0.0f,0.0f};
      #pragma unroll
      for (int kc = 0; kc < 4; kc++){
        f16x8 av = *(const f16x8*)&sAf[(mt*16+n)*136 + kc*32 + q*8];
        f16x8 bv = *(const f16x8*)&w1b[((kc*7+nt)*64 + lane)*8];
        acc = __builtin_amdgcn_mfma_f32_16x16x32_f16(av, bv, acc, 0, 0, 0);
      }
      #pragma unroll
      for (int r = 0; r < 4; r++)
        sX1[(mt*16+q*4+r)*X1STR + nt*16+n] = acc[r];
    }
    __syncthreads();
    // ---- C: half-wave nearest-table gather, 1-deep pipelined, 7 batches --
    {
      int half = lane >> 5, L2i = (lane & 31)*2;   // feature base (even)
      int a = wv*2 + half, ar = a*KEDGE;
      float ag0=0.0f, ag1=0.0f, ag2=0.0f, ag3=0.0f;
      f16x2 PA[4][2]; int jA[4];
      f16x2 PB[4][2]; int jB[4];

#define GLD(E0, P, JV)                                                 \
      { _Pragma("unroll")                                              \
        for (int u = 0; u < 4; u++){                                   \
          int e = ar + (E0) + u;                                       \
          const _Float16* rp = tb + (sOffC[e] + L2i);                  \
          JV[u] = sJx[e];                                              \
          P[u][0] = *(const f16x2*)rp;                                 \
          P[u][1] = *(const f16x2*)(rp + 64);                          \
        } }
#define GCMP(P, JV)                                                    \
      { _Pragma("unroll")                                              \
        for (int u = 0; u < 4; u++){                                   \
          const float* xp = &sX1[JV[u]*X1STR + L2i];                   \
          f32x2 x0 = *(const f32x2*)xp;                                \
          f32x2 x1v = *(const f32x2*)(xp + 64);                        \
          ag0 += (float)P[u][0].x * x0.x;                              \
          ag1 += (float)P[u][0].y * x0.y;                              \
          ag2 += (float)P[u][1].x * x1v.x;                             \
          ag3 += (float)P[u][1].y * x1v.y;                             \
        } }

      GLD(0, PA, jA)
      #pragma unroll
      for (int b = 0; b < 7; b += 2){
        if (b+1 < 7) GLD((b+1)*4, PB, jB)
        GCMP(PA, jA)
        if (b+2 < 7) GLD((b+2)*4, PA, jA)
        if (b+1 < 7) GCMP(PB, jB)
      }
#undef GLD
#undef GCMP
      // features (L2i, L2i+1, L2i+64, L2i+65): cols 0..127 covered exactly
      *(f16x2*)&sAf[a*136 + L2i]      = (f16x2){(_Float16)ag0,(_Float16)ag1};
      *(f16x2*)&sAf[a*136 + 64 + L2i] = (f16x2){(_Float16)ag2,(_Float16)ag3};
    }
    __syncthreads();
    // ---- D: t2 = ssp(agg @ lin2 + b2l) -> sBf f16 ----
    for (int tau = wv; tau < 14; tau += NWAVES){
      int mt = tau/7, nt = tau - mt*7;
      f32x4 acc = {0.0f,0.0f,0.0f,0.0f};
      #pragma unroll
      for (int kc = 0; kc < 4; kc++){
        f16x8 av = *(const f16x8*)&sAf[(mt*16+n)*136 + kc*32 + q*8];
        f16x8 bv = *(const f16x8*)&w2b[((kc*7+nt)*64 + lane)*8];
        acc = __builtin_amdgcn_mfma_f32_16x16x32_f16(av, bv, acc, 0, 0, 0);
      }
      int f = nt*16 + n;
      float bb = (f < FEAT) ? lin2_b[l*FEAT + f] : 0.0f;
      #pragma unroll
      for (int r = 0; r < 4; r++)
        sBf[(mt*16+q*4+r)*136 + f] = (_Float16)sspf(acc[r] + bb);
    }
    __syncthreads();
    // ---- E: v = t2 @ lin + bl ; h += v ; sAf = f16(h) ----
    for (int tau = wv; tau < 14; tau += NWAVES){
      int mt = tau/7, nt = tau - mt*7;
      f32x4 acc = {0.0f,0.0f,0.0f,0.0f};
      #pragma unroll
      for (int kc = 0; kc < 4; kc++){
        f16x8 av = *(const f16x8*)&sBf[(mt*16+n)*136 + kc*32 + q*8];
        f16x8 bv = *(const f16x8*)&wvb[((kc*7+nt)*64 + lane)*8];
        acc = __builtin_amdgcn_mfma_f32_16x16x32_f16(av, bv, acc, 0, 0, 0);
      }
      int f = nt*16 + n;
      if (f < FEAT){
        float bb = lin_b[l*FEAT + f];
        #pragma unroll
        for (int r = 0; r < 4; r++){
          int row = mt*16 + q*4 + r;
          float hn = sH[row*NPAD + f] + acc[r] + bb;
          sH[row*NPAD + f] = hn;
          sAf[row*136 + f] = (_Float16)hn;
        }
      }
    }
    __syncthreads();
  }

  // ---------------- readout (weights direct from L2) ----------------
  float ob2 = out_b2[0];
  float partial = 0.0f;
  for (int t = 0; t < 2; t++){
    int a = wv*2 + t;
    float u = 0.0f;
    if (lane < 50){
      u = out_b1[lane];
      #pragma unroll 4
      for (int c = 0; c < FEAT; c++)
        u += sH[a*NPAD + c] * out_w1[c*50 + lane];
      u = sspf(u) * out_w2[lane];
    }
    #pragma unroll
    for (int s = 1; s < 64; s <<= 1) u += __shfl_xor(u, s);
    partial += u + ob2;
  }
  if (lane == 0) sPart[wv] = partial;
  __syncthreads();
  if (tid == 0){
    float s = 0.0f;
    #pragma unroll
    for (int i = 0; i < NWAVES; i++) s += sPart[i];
    out[mol] = s;
  }
}

extern "C" void kernel_launch(void* const* d_in, const int* in_sizes, int n_in,
                              void* d_out, int out_size, void* d_ws, size_t ws_size,
                              hipStream_t stream)
{
  const int*   z      = (const int*)  d_in[0];
  const float* pos    = (const float*)d_in[1];
  /* d_in[2] = ptr: molecules are fixed 32-atom blocks; unused */
  const float* emb    = (const float*)d_in[3];
  const float* mlp_w1 = (const float*)d_in[4];
  const float* mlp_b1 = (const float*)d_in[5];
  const float* mlp_w2 = (const float*)d_in[6];
  const float* mlp_b2 = (const float*)d_in[7];
  const float* lin1_w = (const float*)d_in[8];
  const float* lin2_w = (const float*)d_in[9];
  const float* lin2_b = (const float*)d_in[10];
  const float* lin_w  = (const float*)d_in[11];
  const float* lin_b  = (const float*)d_in[12];
  const float* out_w1 = (const float*)d_in[13];
  const float* out_b1 = (const float*)d_in[14];
  const float* out_w2 = (const float*)d_in[15];
  const float* out_b2 = (const float*)d_in[16];

  _Float16* wfrag = (_Float16*)d_ws;                      // 344064 B
  _Float16* tbn   = (_Float16*)((char*)d_ws + WTOTAL*2);  // 4*4096*128*2 = 4MB

  prep_all<<<PREP_BLOCKS + TBL_BLOCKS, 256, 0, stream>>>(
      lin1_w, lin2_w, lin_w, mlp_w1, mlp_b1, mlp_w2, mlp_b2, wfrag, tbn);
  schnet_mega<<<NMOL, NTHREADS, 0, stream>>>(z, pos, emb, wfrag, tbn,
      lin2_b, lin_b, out_w1, out_b1, out_w2, out_b2, (float*)d_out);
}